// Round 1
// baseline (79.863 us; speedup 1.0000x reference)
//
#include <hip/hip_runtime.h>

typedef __attribute__((ext_vector_type(8))) short short8;
typedef __attribute__((ext_vector_type(4))) float f32x4;

#define N_IN  4096
#define N_OUT 4096
#define NBAT  256

#define OUT_ACT   0
#define OUT_FICT  1048576
#define OUT_PHYS  2097152
#define OUT_LUT   3145728
#define OUT_TLAST 3211264

#define BM 128
#define BN 32
#define BK 64
#define NT (N_IN / BK)   // 64 K-tiles

__device__ __forceinline__ unsigned f2bf(float f) {
  unsigned u = __float_as_uint(f);
  return (u + 0x7FFFu + ((u >> 16) & 1u)) >> 16;   // RNE to bf16
}

// ---------------------------------------------------------------------------
// Kernel A: per-batch prepass. XOR-parity of masked ids, delta_t, t_last_new.
// ---------------------------------------------------------------------------
__global__ __launch_bounds__(256) void snn_pre(
    const int* __restrict__ mask, const int* __restrict__ t_ptr,
    const int* __restrict__ pid, const int* __restrict__ t_last,
    float* __restrict__ dtf_ws, int* __restrict__ dxa_ws,
    float* __restrict__ out)
{
  const int b = blockIdx.x, tid = threadIdx.x;
  int x = 0;
#pragma unroll
  for (int i = 0; i < 16; ++i) {
    int e = tid + i * 256;
    int m = mask[(size_t)b * N_IN + e];
    int id = pid[e];
    x ^= m ? id : 0;
  }
  x ^= __shfl_xor(x, 32);
  x ^= __shfl_xor(x, 16);
  x ^= __shfl_xor(x, 8);
  x ^= __shfl_xor(x, 4);
  x ^= __shfl_xor(x, 2);
  x ^= __shfl_xor(x, 1);
  __shared__ int wx[4];
  if ((tid & 63) == 0) wx[tid >> 6] = x;
  __syncthreads();
  if (tid == 0) {
    int acc = wx[0] ^ wx[1] ^ wx[2] ^ wx[3];
    int tt = t_ptr[0];
    int dt = (tt - t_last[b]) & 15;
    dtf_ws[b] = (float)dt;
    dxa_ws[b] = dt ^ (acc & 15);
    out[OUT_TLAST + b] = (float)tt;
  }
}

// ---------------------------------------------------------------------------
// Kernel B: bf16 MFMA GEMM (mask @ syn_w) + fused epilogue.
// ---------------------------------------------------------------------------
__global__ __launch_bounds__(256) void snn_gemm(
    const int* __restrict__ mask, const float* __restrict__ synw,
    const float* __restrict__ memf, const int* __restrict__ memp,
    const float* __restrict__ tau, const float* __restrict__ vth,
    const float* __restrict__ mem_map,
    const float* __restrict__ dtf_ws, const int* __restrict__ dxa_ws,
    float* __restrict__ out)
{
  __shared__ __align__(16) char ldsA[2][BM * BK * 2];  // 2 x 16 KB bf16
  __shared__ __align__(16) char ldsB[2][BN * BK * 2];  // 2 x  4 KB bf16 (n-major, k contiguous)

  const int tid = threadIdx.x;
  const int lane = tid & 63, wid = tid >> 6;
  const int l15 = lane & 15, l4 = lane >> 4;
  const int bnb = blockIdx.x * BN;
  const int bmb = blockIdx.y * BM;

  // A staging: thread covers rows a_r0 + i*32 (i=0..3), k-group a_kg (8 elems)
  const int a_kg = tid & 7;
  const int a_r0 = tid >> 3;            // 0..31
  // B staging: thread covers column b_n, k = b_k0..b_k0+7
  const int b_n = tid & 31;
  const int b_k0 = (tid >> 5) * 8;      // 0..56

  int4 aReg[4][2];
  float bReg[8];

  auto issue_loads = [&](int kt) {
    const int kbase = kt * BK;
#pragma unroll
    for (int i = 0; i < 4; ++i) {
      int row = a_r0 + i * 32;
      const int* p = mask + (size_t)(bmb + row) * N_IN + kbase + a_kg * 8;
      aReg[i][0] = *(const int4*)p;
      aReg[i][1] = *(const int4*)(p + 4);
    }
#pragma unroll
    for (int j = 0; j < 8; ++j)
      bReg[j] = synw[(size_t)(kbase + b_k0 + j) * N_OUT + bnb + b_n];
  };

  auto write_lds = [&](int buf) {
#pragma unroll
    for (int i = 0; i < 4; ++i) {
      int row = a_r0 + i * 32;
      int g = a_kg ^ (row & 7);
      int4 lo = aReg[i][0], hi = aReg[i][1];
      uint4 v;
      v.x = (lo.x ? 0x3F80u : 0u) | ((lo.y ? 0x3F80u : 0u) << 16);
      v.y = (lo.z ? 0x3F80u : 0u) | ((lo.w ? 0x3F80u : 0u) << 16);
      v.z = (hi.x ? 0x3F80u : 0u) | ((hi.y ? 0x3F80u : 0u) << 16);
      v.w = (hi.z ? 0x3F80u : 0u) | ((hi.w ? 0x3F80u : 0u) << 16);
      *(uint4*)(&ldsA[buf][row * 128 + g * 16]) = v;
    }
    {
      int g = (b_k0 >> 3) ^ (b_n & 7);
      uint4 v;
      v.x = f2bf(bReg[0]) | (f2bf(bReg[1]) << 16);
      v.y = f2bf(bReg[2]) | (f2bf(bReg[3]) << 16);
      v.z = f2bf(bReg[4]) | (f2bf(bReg[5]) << 16);
      v.w = f2bf(bReg[6]) | (f2bf(bReg[7]) << 16);
      *(uint4*)(&ldsB[buf][b_n * 128 + g * 16]) = v;
    }
  };

  f32x4 acc[2][2] = {};

  auto compute = [&](int buf) {
#pragma unroll
    for (int kk = 0; kk < 2; ++kk) {
      int g0 = kk * 4 + l4;     // 16B unit within the 64-k row
      short8 a[2], b[2];
#pragma unroll
      for (int mi = 0; mi < 2; ++mi) {
        int row = wid * 32 + mi * 16 + l15;
        a[mi] = *(const short8*)(&ldsA[buf][row * 128 + ((g0 ^ (row & 7)) * 16)]);
      }
#pragma unroll
      for (int nj = 0; nj < 2; ++nj) {
        int n = nj * 16 + l15;
        b[nj] = *(const short8*)(&ldsB[buf][n * 128 + ((g0 ^ (n & 7)) * 16)]);
      }
#pragma unroll
      for (int mi = 0; mi < 2; ++mi)
#pragma unroll
        for (int nj = 0; nj < 2; ++nj)
          acc[mi][nj] = __builtin_amdgcn_mfma_f32_16x16x32_bf16(
              a[mi], b[nj], acc[mi][nj], 0, 0, 0);
    }
  };

  // prologue
  issue_loads(0);
  write_lds(0);
  __syncthreads();

  for (int kt = 0; kt < NT; ++kt) {
    int cur = kt & 1;
    if (kt + 1 < NT) issue_loads(kt + 1);   // issue early: latency hides under compute
    compute(cur);
    if (kt + 1 < NT) write_lds(cur ^ 1);    // auto vmcnt wait on reg deps
    __syncthreads();
  }

  // fused epilogue
#pragma unroll
  for (int mi = 0; mi < 2; ++mi) {
#pragma unroll
    for (int r = 0; r < 4; ++r) {
      int b = bmb + wid * 32 + mi * 16 + l4 * 4 + r;
      float dtf = dtf_ws[b];
      int dxa = dxa_ws[b];
#pragma unroll
      for (int nj = 0; nj < 2; ++nj) {
        int o = bnb + nj * 16 + l15;
        size_t idx = (size_t)b * N_OUT + o;
        float wsv = acc[mi][nj][r];
        float fict = memf[idx];
        int mpv = memp[idx];
        float decay = __expf(-tau[o] * dtf);
        float fnew = fict * decay + wsv;
        int mpn = (mpv ^ dxa) & 15;
        float vmap = mem_map[o * 16 + mpn];
        out[OUT_ACT + idx] = (vmap >= vth[o]) ? 1.0f : 0.0f;
        out[OUT_FICT + idx] = fnew;
        out[OUT_PHYS + idx] = (float)mpn;
      }
    }
  }
}

// ---------------------------------------------------------------------------
// Kernel C: LUT scatter-add collapsed to per-(o,m) histogram.
// lut_new[o][m] = lut_in[o][m] + 0.5*(m - mem_map[o][m]) * count[o][m]
// ---------------------------------------------------------------------------
__global__ __launch_bounds__(256) void snn_lut(
    const int* __restrict__ memp, const int* __restrict__ dxa_ws,
    const float* __restrict__ mem_map, const float* __restrict__ lut_in,
    float* __restrict__ out)
{
  __shared__ int mp[NBAT * 16];   // [b][o_local], 16 KB
  __shared__ int dxs[NBAT];
  const int tid = threadIdx.x;
  const int o0 = blockIdx.x * 16;

#pragma unroll
  for (int i = 0; i < 16; ++i) {
    int b = i * 16 + (tid >> 4);
    int oj = tid & 15;
    mp[b * 16 + oj] = memp[(size_t)b * N_OUT + o0 + oj];
  }
  dxs[tid] = dxa_ws[tid];
  __syncthreads();

  const int o_l = tid >> 4, m = tid & 15;
  int cnt = 0;
#pragma unroll 8
  for (int b = 0; b < NBAT; ++b) {
    int v = (mp[b * 16 + o_l] ^ dxs[b]) & 15;
    cnt += (v == m);
  }
  int o = o0 + o_l;
  float vmap = mem_map[o * 16 + m];
  out[OUT_LUT + o * 16 + m] =
      lut_in[o * 16 + m] + 0.5f * ((float)m - vmap) * (float)cnt;
}

// ---------------------------------------------------------------------------
extern "C" void kernel_launch(void* const* d_in, const int* in_sizes, int n_in,
                              void* d_out, int out_size, void* d_ws, size_t ws_size,
                              hipStream_t stream)
{
  const int*   mask    = (const int*)d_in[0];
  const int*   t_ptr   = (const int*)d_in[1];
  const int*   pid     = (const int*)d_in[2];
  const int*   t_last  = (const int*)d_in[3];
  const float* memf    = (const float*)d_in[4];
  const int*   memp    = (const int*)d_in[5];
  const float* lut_in  = (const float*)d_in[6];
  const float* tau     = (const float*)d_in[7];
  const float* vth     = (const float*)d_in[8];
  const float* synw    = (const float*)d_in[9];
  const float* mem_map = (const float*)d_in[10];
  float* out = (float*)d_out;

  float* dtf_ws = (float*)d_ws;
  int*   dxa_ws = (int*)((char*)d_ws + 1024);

  snn_pre<<<NBAT, 256, 0, stream>>>(mask, t_ptr, pid, t_last, dtf_ws, dxa_ws, out);
  snn_gemm<<<dim3(N_OUT / BN, NBAT / BM), 256, 0, stream>>>(
      mask, synw, memf, memp, tau, vth, mem_map, dtf_ws, dxa_ws, out);
  snn_lut<<<NBAT, 256, 0, stream>>>(memp, dxa_ws, mem_map, lut_in, out);
}

// Round 2
// 52.671 us; speedup vs baseline: 1.5163x; 1.5163x over previous
//
#include <hip/hip_runtime.h>

typedef __attribute__((ext_vector_type(8))) short short8;
typedef __attribute__((ext_vector_type(4))) float f32x4;
typedef unsigned int u32;

#define N_IN  4096
#define N_OUT 4096
#define NBAT  256

#define OUT_ACT   0
#define OUT_FICT  1048576
#define OUT_PHYS  2097152
#define OUT_LUT   3145728
#define OUT_TLAST 3211264

// ws layout
#define WS_MASK   0                       // 2 MB bf16 mask, pre-swizzled
#define WS_PART   2097152                 // 16 MB fp32 partials [4][256][4096]
#define WS_DTF    (WS_PART + 16777216)
#define WS_DXA    (WS_DTF + 1024)

#define BM 128
#define BN 64
#define BK 64
#define SPLITK 4
#define KCHUNK (N_IN / SPLITK)            // 1024
#define NTK (KCHUNK / BK)                 // 16 K-tiles per block

__device__ __forceinline__ unsigned f2bf(float f) {
  unsigned u = __float_as_uint(f);
  return (u + 0x7FFFu + ((u >> 16) & 1u)) >> 16;   // RNE to bf16
}

__device__ __forceinline__ void gload16(const void* g, void* l) {
  __builtin_amdgcn_global_load_lds(
      (const __attribute__((address_space(1))) u32*)g,
      (__attribute__((address_space(3))) u32*)l, 16, 0, 0);
}

// ---------------------------------------------------------------------------
// Kernel A: prepass. XOR-parity + delta_t + t_last, AND converts mask to a
// pre-swizzled bf16 image (swizzle: 16B unit g' = g ^ (row&7) within each
// 64-k tile) so the GEMM can global_load_lds it linearly and read swizzled.
// ---------------------------------------------------------------------------
__global__ __launch_bounds__(256) void snn_pre(
    const int* __restrict__ mask, const int* __restrict__ t_ptr,
    const int* __restrict__ pid, const int* __restrict__ t_last,
    float* __restrict__ dtf_ws, int* __restrict__ dxa_ws,
    u32* __restrict__ maskws, float* __restrict__ out)
{
  const int b = blockIdx.x, tid = threadIdx.x;
  const int k0 = tid * 16;
  const int4* mp = (const int4*)(mask + (size_t)b * N_IN + k0);
  const int4* pp = (const int4*)(pid + k0);
  int x = 0;
  u32 wv[8];
#pragma unroll
  for (int q = 0; q < 4; ++q) {
    int4 m = mp[q];
    int4 id = pp[q];
    x ^= (m.x ? id.x : 0) ^ (m.y ? id.y : 0) ^ (m.z ? id.z : 0) ^ (m.w ? id.w : 0);
    wv[q * 2]     = (m.x ? 0x3F80u : 0u) | ((m.y ? 0x3F80u : 0u) << 16);
    wv[q * 2 + 1] = (m.z ? 0x3F80u : 0u) | ((m.w ? 0x3F80u : 0u) << 16);
  }
  // write two swizzled 16B units
  {
    const int kt = tid >> 2;            // 64-k tile index
    const int gg = (tid & 3) * 2;       // 16B unit within tile
    u32* base = maskws + (size_t)b * 2048 + kt * 32;   // row stride 8192B
    int g0 = gg ^ (b & 7), g1 = (gg + 1) ^ (b & 7);
    uint4 v0; v0.x = wv[0]; v0.y = wv[1]; v0.z = wv[2]; v0.w = wv[3];
    uint4 v1; v1.x = wv[4]; v1.y = wv[5]; v1.z = wv[6]; v1.w = wv[7];
    *(uint4*)(base + g0 * 4) = v0;
    *(uint4*)(base + g1 * 4) = v1;
  }
  x ^= __shfl_xor(x, 32); x ^= __shfl_xor(x, 16); x ^= __shfl_xor(x, 8);
  x ^= __shfl_xor(x, 4);  x ^= __shfl_xor(x, 2);  x ^= __shfl_xor(x, 1);
  __shared__ int wx[4];
  if ((tid & 63) == 0) wx[tid >> 6] = x;
  __syncthreads();
  if (tid == 0) {
    int acc = wx[0] ^ wx[1] ^ wx[2] ^ wx[3];
    int tt = t_ptr[0];
    int dt = (tt - t_last[b]) & 15;
    dtf_ws[b] = (float)dt;
    dxa_ws[b] = dt ^ (acc & 15);
    out[OUT_TLAST + b] = (float)tt;
  }
}

// ---------------------------------------------------------------------------
// Kernel B: bf16 MFMA GEMM, split-K=4, writes fp32 partials.
// A: global_load_lds (16B) from pre-swizzled maskws. B: reg-staged fp32->bf16.
// ---------------------------------------------------------------------------
__global__ __launch_bounds__(256) void snn_gemm(
    const char* __restrict__ maskws, const float* __restrict__ synw,
    float* __restrict__ part)
{
  __shared__ __align__(16) char ldsA[2][BM * BK * 2];   // 16 KB each
  __shared__ __align__(16) char ldsB[2][BN * BK * 2];   //  8 KB each

  const int tid = threadIdx.x;
  const int lane = tid & 63, wid = tid >> 6;
  const int l15 = lane & 15, l4 = lane >> 4;
  const int mb = blockIdx.x, nb = blockIdx.y, sp = blockIdx.z;
  const int bmb = mb * BM, bnb = nb * BN, kcb = sp * KCHUNK;
  const int wm = wid >> 1, wn = wid & 1;   // 2x2 wave grid, wave tile 64x32

  // A staging: 4 global_load_lds issues/K-tile; lds unit u=i*256+tid -> row=u>>3, g=u&7
  const char* a_gbase = maskws + (size_t)bmb * 8192 + (size_t)kcb * 2;
  // B staging: n = tid&63, k-quarter = tid>>6 (16 k-rows each)
  const int b_n = tid & 63;
  const int b_kq = tid >> 6;
  const float* b_gbase = synw + (size_t)(kcb + b_kq * 16) * N_OUT + bnb + b_n;
  float bv[16];

  auto issueA = [&](int buf, int kt) {
#pragma unroll
    for (int i = 0; i < 4; ++i) {
      const char* g = a_gbase + (size_t)(i * 32 + (tid >> 3)) * 8192 + kt * 128 + (tid & 7) * 16;
      gload16(g, &ldsA[buf][i * 4096 + wid * 1024]);   // wave-uniform lds base + lane*16
    }
  };
  auto loadB = [&](int kt) {
    const float* g = b_gbase + (size_t)kt * BK * N_OUT;
#pragma unroll
    for (int j = 0; j < 16; ++j) bv[j] = g[(size_t)j * N_OUT];
  };
  auto writeB = [&](int buf) {
    u32 w[8];
#pragma unroll
    for (int p = 0; p < 8; ++p) w[p] = f2bf(bv[2 * p]) | (f2bf(bv[2 * p + 1]) << 16);
    const int gb = b_kq * 2, s = b_n & 7;
    uint4 v0; v0.x = w[0]; v0.y = w[1]; v0.z = w[2]; v0.w = w[3];
    uint4 v1; v1.x = w[4]; v1.y = w[5]; v1.z = w[6]; v1.w = w[7];
    *(uint4*)(&ldsB[buf][b_n * 128 + ((gb ^ s) * 16)]) = v0;
    *(uint4*)(&ldsB[buf][b_n * 128 + (((gb + 1) ^ s) * 16)]) = v1;
  };

  f32x4 acc[4][2] = {};

  auto compute = [&](int buf) {
#pragma unroll
    for (int kk = 0; kk < 2; ++kk) {
      const int g0 = kk * 4 + l4;
      short8 a[4], b[2];
#pragma unroll
      for (int mi = 0; mi < 4; ++mi) {
        int row = wm * 64 + mi * 16 + l15;
        a[mi] = *(const short8*)(&ldsA[buf][row * 128 + ((g0 ^ (row & 7)) * 16)]);
      }
#pragma unroll
      for (int nj = 0; nj < 2; ++nj) {
        int col = wn * 32 + nj * 16 + l15;
        b[nj] = *(const short8*)(&ldsB[buf][col * 128 + ((g0 ^ (col & 7)) * 16)]);
      }
#pragma unroll
      for (int mi = 0; mi < 4; ++mi)
#pragma unroll
        for (int nj = 0; nj < 2; ++nj)
          acc[mi][nj] = __builtin_amdgcn_mfma_f32_16x16x32_bf16(a[mi], b[nj], acc[mi][nj], 0, 0, 0);
    }
  };

  issueA(0, 0); loadB(0); writeB(0);
  __syncthreads();

  for (int kt = 0; kt < NTK; ++kt) {
    const int cur = kt & 1;
    if (kt + 1 < NTK) { issueA(cur ^ 1, kt + 1); loadB(kt + 1); }
    compute(cur);
    if (kt + 1 < NTK) writeB(cur ^ 1);
    __syncthreads();   // drains vmcnt(0): A lds-loads complete
  }

  float* pb = part + (size_t)sp * (NBAT * N_OUT);
#pragma unroll
  for (int mi = 0; mi < 4; ++mi)
#pragma unroll
    for (int nj = 0; nj < 2; ++nj) {
      const int o = bnb + wn * 32 + nj * 16 + l15;
#pragma unroll
      for (int r = 0; r < 4; ++r) {
        const int b = bmb + wm * 64 + mi * 16 + l4 * 4 + r;
        pb[(size_t)b * N_OUT + o] = acc[mi][nj][r];
      }
    }
}

// ---------------------------------------------------------------------------
// Kernel C: split-K reduce + fused epilogue (decay, phys, act).
// ---------------------------------------------------------------------------
__global__ __launch_bounds__(256) void snn_reduce(
    const float* __restrict__ part, const float* __restrict__ memf,
    const int* __restrict__ memp, const float* __restrict__ tau,
    const float* __restrict__ vth, const float* __restrict__ mem_map,
    const float* __restrict__ dtf_ws, const int* __restrict__ dxa_ws,
    float* __restrict__ out)
{
  const int flat = (blockIdx.x * 256 + threadIdx.x) * 4;
  const int b = flat >> 12, o = flat & 4095;
  const float4 p0 = *(const float4*)(part + flat);
  const float4 p1 = *(const float4*)(part + 1048576 + flat);
  const float4 p2 = *(const float4*)(part + 2097152 + flat);
  const float4 p3 = *(const float4*)(part + 3145728 + flat);
  float4 ws;
  ws.x = (p0.x + p1.x) + (p2.x + p3.x);
  ws.y = (p0.y + p1.y) + (p2.y + p3.y);
  ws.z = (p0.z + p1.z) + (p2.z + p3.z);
  ws.w = (p0.w + p1.w) + (p2.w + p3.w);
  const float dtf = dtf_ws[b];
  const int dxa = dxa_ws[b];
  const float4 mf = *(const float4*)(memf + flat);
  const int4  mp = *(const int4*)(memp + flat);
  const float4 tv = *(const float4*)(tau + o);
  const float4 vv = *(const float4*)(vth + o);
  float4 act, fict, phys;
#define DO(c, oi) { float d = __expf(-tv.c * dtf); fict.c = mf.c * d + ws.c; \
                    int mpn = (mp.c ^ dxa) & 15; phys.c = (float)mpn; \
                    act.c = (mem_map[(o + oi) * 16 + mpn] >= vv.c) ? 1.f : 0.f; }
  DO(x, 0) DO(y, 1) DO(z, 2) DO(w, 3)
#undef DO
  *(float4*)(out + OUT_ACT  + flat) = act;
  *(float4*)(out + OUT_FICT + flat) = fict;
  *(float4*)(out + OUT_PHYS + flat) = phys;
}

// ---------------------------------------------------------------------------
// Kernel D: LUT scatter-add collapsed to per-(o,m) histogram.
// ---------------------------------------------------------------------------
__global__ __launch_bounds__(256) void snn_lut(
    const int* __restrict__ memp, const int* __restrict__ dxa_ws,
    const float* __restrict__ mem_map, const float* __restrict__ lut_in,
    float* __restrict__ out)
{
  __shared__ int mp[NBAT * 16];
  __shared__ int dxs[NBAT];
  const int tid = threadIdx.x;
  const int o0 = blockIdx.x * 16;
#pragma unroll
  for (int i = 0; i < 16; ++i) {
    int b = i * 16 + (tid >> 4);
    int oj = tid & 15;
    mp[b * 16 + oj] = memp[(size_t)b * N_OUT + o0 + oj];
  }
  dxs[tid] = dxa_ws[tid];
  __syncthreads();
  const int o_l = tid >> 4, m = tid & 15;
  int cnt = 0;
#pragma unroll 8
  for (int b = 0; b < NBAT; ++b) {
    int v = (mp[b * 16 + o_l] ^ dxs[b]) & 15;
    cnt += (v == m);
  }
  const int o = o0 + o_l;
  const float vmap = mem_map[o * 16 + m];
  out[OUT_LUT + o * 16 + m] = lut_in[o * 16 + m] + 0.5f * ((float)m - vmap) * (float)cnt;
}

// ---------------------------------------------------------------------------
extern "C" void kernel_launch(void* const* d_in, const int* in_sizes, int n_in,
                              void* d_out, int out_size, void* d_ws, size_t ws_size,
                              hipStream_t stream)
{
  const int*   mask    = (const int*)d_in[0];
  const int*   t_ptr   = (const int*)d_in[1];
  const int*   pid     = (const int*)d_in[2];
  const int*   t_last  = (const int*)d_in[3];
  const float* memf    = (const float*)d_in[4];
  const int*   memp    = (const int*)d_in[5];
  const float* lut_in  = (const float*)d_in[6];
  const float* tau     = (const float*)d_in[7];
  const float* vth     = (const float*)d_in[8];
  const float* synw    = (const float*)d_in[9];
  const float* mem_map = (const float*)d_in[10];
  float* out = (float*)d_out;

  char* wsb = (char*)d_ws;
  u32*   maskws = (u32*)(wsb + WS_MASK);
  float* part   = (float*)(wsb + WS_PART);
  float* dtf_ws = (float*)(wsb + WS_DTF);
  int*   dxa_ws = (int*)(wsb + WS_DXA);

  snn_pre<<<NBAT, 256, 0, stream>>>(mask, t_ptr, pid, t_last, dtf_ws, dxa_ws, maskws, out);
  snn_gemm<<<dim3(NBAT / BM, N_OUT / BN, SPLITK), 256, 0, stream>>>(
      (const char*)maskws, synw, part);
  snn_reduce<<<(NBAT * N_OUT) / 1024, 256, 0, stream>>>(
      part, memf, memp, tau, vth, mem_map, dtf_ws, dxa_ws, out);
  snn_lut<<<NBAT, 256, 0, stream>>>(memp, dxa_ws, mem_map, lut_in, out);
}

// Round 3
// 50.846 us; speedup vs baseline: 1.5707x; 1.0359x over previous
//
#include <hip/hip_runtime.h>

typedef __attribute__((ext_vector_type(8))) short short8;
typedef __attribute__((ext_vector_type(4))) float f32x4;
typedef unsigned int u32;

#define N_IN  4096
#define N_OUT 4096
#define NBAT  256

#define OUT_ACT   0
#define OUT_FICT  1048576
#define OUT_PHYS  2097152
#define OUT_LUT   3145728
#define OUT_TLAST 3211264

// ws layout
#define WS_MASK   0                       // 2 MB bf16 mask, pre-swizzled
#define WS_PART   2097152                 // 16 MB fp32 partials [4][256][4096]
#define WS_DTF    (WS_PART + 16777216)
#define WS_DXA    (WS_DTF + 1024)

#define BM 128
#define BN 64
#define BK 64
#define SPLITK 4
#define KCHUNK (N_IN / SPLITK)            // 1024
#define NTK (KCHUNK / BK)                 // 16 K-tiles per block

__device__ __forceinline__ unsigned f2bf(float f) {
  unsigned u = __float_as_uint(f);
  return (u + 0x7FFFu + ((u >> 16) & 1u)) >> 16;   // RNE to bf16
}

__device__ __forceinline__ void gload16(const void* g, void* l) {
  __builtin_amdgcn_global_load_lds(
      (const __attribute__((address_space(1))) u32*)g,
      (__attribute__((address_space(3))) u32*)l, 16, 0, 0);
}

// ---------------------------------------------------------------------------
// Kernel A: prepass. XOR-parity + delta_t + t_last, AND converts mask to a
// pre-swizzled bf16 image (16B unit g' = g ^ (row&7) within each 64-k tile)
// so the GEMM can global_load_lds it linearly and read swizzled.
// ---------------------------------------------------------------------------
__global__ __launch_bounds__(256) void snn_pre(
    const int* __restrict__ mask, const int* __restrict__ t_ptr,
    const int* __restrict__ pid, const int* __restrict__ t_last,
    float* __restrict__ dtf_ws, int* __restrict__ dxa_ws,
    u32* __restrict__ maskws, float* __restrict__ out)
{
  const int b = blockIdx.x, tid = threadIdx.x;
  const int k0 = tid * 16;
  const int4* mp = (const int4*)(mask + (size_t)b * N_IN + k0);
  const int4* pp = (const int4*)(pid + k0);
  int x = 0;
  u32 wv[8];
#pragma unroll
  for (int q = 0; q < 4; ++q) {
    int4 m = mp[q];
    int4 id = pp[q];
    x ^= (m.x ? id.x : 0) ^ (m.y ? id.y : 0) ^ (m.z ? id.z : 0) ^ (m.w ? id.w : 0);
    wv[q * 2]     = (m.x ? 0x3F80u : 0u) | ((m.y ? 0x3F80u : 0u) << 16);
    wv[q * 2 + 1] = (m.z ? 0x3F80u : 0u) | ((m.w ? 0x3F80u : 0u) << 16);
  }
  {
    const int kt = tid >> 2;            // 64-k tile index
    const int gg = (tid & 3) * 2;       // 16B unit within tile
    u32* base = maskws + (size_t)b * 2048 + kt * 32;   // row stride 8192B
    int g0 = gg ^ (b & 7), g1 = (gg + 1) ^ (b & 7);
    uint4 v0; v0.x = wv[0]; v0.y = wv[1]; v0.z = wv[2]; v0.w = wv[3];
    uint4 v1; v1.x = wv[4]; v1.y = wv[5]; v1.z = wv[6]; v1.w = wv[7];
    *(uint4*)(base + g0 * 4) = v0;
    *(uint4*)(base + g1 * 4) = v1;
  }
  x ^= __shfl_xor(x, 32); x ^= __shfl_xor(x, 16); x ^= __shfl_xor(x, 8);
  x ^= __shfl_xor(x, 4);  x ^= __shfl_xor(x, 2);  x ^= __shfl_xor(x, 1);
  __shared__ int wx[4];
  if ((tid & 63) == 0) wx[tid >> 6] = x;
  __syncthreads();
  if (tid == 0) {
    int acc = wx[0] ^ wx[1] ^ wx[2] ^ wx[3];
    int tt = t_ptr[0];
    int dt = (tt - t_last[b]) & 15;
    dtf_ws[b] = (float)dt;
    dxa_ws[b] = dt ^ (acc & 15);
    out[OUT_TLAST + b] = (float)tt;
  }
}

// ---------------------------------------------------------------------------
// Kernel B: bf16 MFMA GEMM, split-K=4, software-pipelined:
//   A: global_load_lds depth-2 into 3-deep LDS ring (pre-swizzled image)
//   B: reg-staged fp32->bf16, depth-1 (2 named reg sets, 2x-unrolled loop)
//   raw s_barrier + lgkmcnt(0) only -- vmcnt stays counted (never drained),
//   so loads for kt+1/kt+2 remain in flight across barriers.
// ---------------------------------------------------------------------------
__global__ __launch_bounds__(256) void snn_gemm(
    const char* __restrict__ maskws, const float* __restrict__ synw,
    float* __restrict__ part)
{
  __shared__ __align__(16) char ldsA[3][BM * BK * 2];   // 3 x 16 KB ring
  __shared__ __align__(16) char ldsB[2][BN * BK * 2];   // 2 x  8 KB

  const int tid = threadIdx.x;
  const int lane = tid & 63, wid = tid >> 6;
  const int l15 = lane & 15, l4 = lane >> 4;
  const int bmb = blockIdx.x * BM, bnb = blockIdx.y * BN;
  const int kcb = blockIdx.z * KCHUNK;
  const int wm = wid >> 1, wn = wid & 1;   // 2x2 wave grid, wave tile 64x32

  const char* a_gbase = maskws + (size_t)bmb * 8192 + (size_t)kcb * 2;
  const int b_n = tid & 63;
  const int b_kq = tid >> 6;
  const float* b_gbase = synw + (size_t)(kcb + b_kq * 16) * N_OUT + bnb + b_n;

  auto issueA = [&](int kt) {
    char* dbase = &ldsA[kt % 3][wid * 1024];
    const char* g0 = a_gbase + (size_t)(tid >> 3) * 8192 + kt * 128 + (tid & 7) * 16;
#pragma unroll
    for (int i = 0; i < 4; ++i)
      gload16(g0 + (size_t)i * (32 * 8192), dbase + i * 4096);
  };
  auto loadB = [&](int kt, float* bv) {
    const float* g = b_gbase + (size_t)kt * BK * N_OUT;
#pragma unroll
    for (int j = 0; j < 16; ++j) bv[j] = g[(size_t)j * N_OUT];
  };
  auto writeB = [&](const float* bv, int buf) {
    u32 w[8];
#pragma unroll
    for (int p = 0; p < 8; ++p) w[p] = f2bf(bv[2 * p]) | (f2bf(bv[2 * p + 1]) << 16);
    const int gb = b_kq * 2, s = b_n & 7;
    uint4 v0; v0.x = w[0]; v0.y = w[1]; v0.z = w[2]; v0.w = w[3];
    uint4 v1; v1.x = w[4]; v1.y = w[5]; v1.z = w[6]; v1.w = w[7];
    *(uint4*)(&ldsB[buf][b_n * 128 + ((gb ^ s) * 16)]) = v0;
    *(uint4*)(&ldsB[buf][b_n * 128 + (((gb + 1) ^ s) * 16)]) = v1;
  };

  f32x4 acc[4][2] = {};

  auto compute = [&](int abuf, int bbuf) {
#pragma unroll
    for (int kk = 0; kk < 2; ++kk) {
      const int g0 = kk * 4 + l4;
      short8 a[4], b[2];
#pragma unroll
      for (int mi = 0; mi < 4; ++mi) {
        int row = wm * 64 + mi * 16 + l15;
        a[mi] = *(const short8*)(&ldsA[abuf][row * 128 + ((g0 ^ (row & 7)) * 16)]);
      }
#pragma unroll
      for (int nj = 0; nj < 2; ++nj) {
        int col = wn * 32 + nj * 16 + l15;
        b[nj] = *(const short8*)(&ldsB[bbuf][col * 128 + ((g0 ^ (col & 7)) * 16)]);
      }
#pragma unroll
      for (int mi = 0; mi < 4; ++mi)
#pragma unroll
        for (int nj = 0; nj < 2; ++nj)
          acc[mi][nj] = __builtin_amdgcn_mfma_f32_16x16x32_bf16(a[mi], b[nj], acc[mi][nj], 0, 0, 0);
    }
  };

  float bvA[16], bvB[16];

  // prologue: A(0), B(0), A(1) in flight
  issueA(0);
  loadB(0, bvA);
  issueA(1);

#define BODY(KT, CURBV, NXTBV)                                   \
  {                                                              \
    if ((KT) + 1 < NTK) loadB((KT) + 1, NXTBV);                  \
    writeB(CURBV, (KT) & 1); /* counted vmcnt: waits B(KT), covers A(KT) */ \
    __builtin_amdgcn_sched_barrier(0);                           \
    asm volatile("s_waitcnt lgkmcnt(0)" ::: "memory");           \
    __builtin_amdgcn_s_barrier();                                \
    __builtin_amdgcn_sched_barrier(0);                           \
    if ((KT) + 2 < NTK) issueA((KT) + 2);                        \
    compute((KT) % 3, (KT) & 1);                                 \
  }

  for (int kt = 0; kt < NTK; kt += 2) {
    BODY(kt, bvA, bvB);
    BODY(kt + 1, bvB, bvA);
  }
#undef BODY

  float* pb = part + (size_t)blockIdx.z * (NBAT * N_OUT);
#pragma unroll
  for (int mi = 0; mi < 4; ++mi)
#pragma unroll
    for (int nj = 0; nj < 2; ++nj) {
      const int o = bnb + wn * 32 + nj * 16 + l15;
#pragma unroll
      for (int r = 0; r < 4; ++r) {
        const int b = bmb + wm * 64 + mi * 16 + l4 * 4 + r;
        pb[(size_t)b * N_OUT + o] = acc[mi][nj][r];
      }
    }
}

// ---------------------------------------------------------------------------
// Kernel C: split-K reduce + fused epilogue (decay, phys, act).
// ---------------------------------------------------------------------------
__global__ __launch_bounds__(256) void snn_reduce(
    const float* __restrict__ part, const float* __restrict__ memf,
    const int* __restrict__ memp, const float* __restrict__ tau,
    const float* __restrict__ vth, const float* __restrict__ mem_map,
    const float* __restrict__ dtf_ws, const int* __restrict__ dxa_ws,
    float* __restrict__ out)
{
  const int flat = (blockIdx.x * 256 + threadIdx.x) * 4;
  const int b = flat >> 12, o = flat & 4095;
  const float4 p0 = *(const float4*)(part + flat);
  const float4 p1 = *(const float4*)(part + 1048576 + flat);
  const float4 p2 = *(const float4*)(part + 2097152 + flat);
  const float4 p3 = *(const float4*)(part + 3145728 + flat);
  float4 ws;
  ws.x = (p0.x + p1.x) + (p2.x + p3.x);
  ws.y = (p0.y + p1.y) + (p2.y + p3.y);
  ws.z = (p0.z + p1.z) + (p2.z + p3.z);
  ws.w = (p0.w + p1.w) + (p2.w + p3.w);
  const float dtf = dtf_ws[b];
  const int dxa = dxa_ws[b];
  const float4 mf = *(const float4*)(memf + flat);
  const int4  mp = *(const int4*)(memp + flat);
  const float4 tv = *(const float4*)(tau + o);
  const float4 vv = *(const float4*)(vth + o);
  float4 act, fict, phys;
#define DO(c, oi) { float d = __expf(-tv.c * dtf); fict.c = mf.c * d + ws.c; \
                    int mpn = (mp.c ^ dxa) & 15; phys.c = (float)mpn; \
                    act.c = (mem_map[(o + oi) * 16 + mpn] >= vv.c) ? 1.f : 0.f; }
  DO(x, 0) DO(y, 1) DO(z, 2) DO(w, 3)
#undef DO
  *(float4*)(out + OUT_ACT  + flat) = act;
  *(float4*)(out + OUT_FICT + flat) = fict;
  *(float4*)(out + OUT_PHYS + flat) = phys;
}

// ---------------------------------------------------------------------------
// Kernel D: LUT scatter-add collapsed to per-(o,m) histogram.
// ---------------------------------------------------------------------------
__global__ __launch_bounds__(256) void snn_lut(
    const int* __restrict__ memp, const int* __restrict__ dxa_ws,
    const float* __restrict__ mem_map, const float* __restrict__ lut_in,
    float* __restrict__ out)
{
  __shared__ int mp[NBAT * 16];
  __shared__ int dxs[NBAT];
  const int tid = threadIdx.x;
  const int o0 = blockIdx.x * 16;
#pragma unroll
  for (int i = 0; i < 16; ++i) {
    int b = i * 16 + (tid >> 4);
    int oj = tid & 15;
    mp[b * 16 + oj] = memp[(size_t)b * N_OUT + o0 + oj];
  }
  dxs[tid] = dxa_ws[tid];
  __syncthreads();
  const int o_l = tid >> 4, m = tid & 15;
  int cnt = 0;
#pragma unroll 8
  for (int b = 0; b < NBAT; ++b) {
    int v = (mp[b * 16 + o_l] ^ dxs[b]) & 15;
    cnt += (v == m);
  }
  const int o = o0 + o_l;
  const float vmap = mem_map[o * 16 + m];
  out[OUT_LUT + o * 16 + m] = lut_in[o * 16 + m] + 0.5f * ((float)m - vmap) * (float)cnt;
}

// ---------------------------------------------------------------------------
extern "C" void kernel_launch(void* const* d_in, const int* in_sizes, int n_in,
                              void* d_out, int out_size, void* d_ws, size_t ws_size,
                              hipStream_t stream)
{
  const int*   mask    = (const int*)d_in[0];
  const int*   t_ptr   = (const int*)d_in[1];
  const int*   pid     = (const int*)d_in[2];
  const int*   t_last  = (const int*)d_in[3];
  const float* memf    = (const float*)d_in[4];
  const int*   memp    = (const int*)d_in[5];
  const float* lut_in  = (const float*)d_in[6];
  const float* tau     = (const float*)d_in[7];
  const float* vth     = (const float*)d_in[8];
  const float* synw    = (const float*)d_in[9];
  const float* mem_map = (const float*)d_in[10];
  float* out = (float*)d_out;

  char* wsb = (char*)d_ws;
  u32*   maskws = (u32*)(wsb + WS_MASK);
  float* part   = (float*)(wsb + WS_PART);
  float* dtf_ws = (float*)(wsb + WS_DTF);
  int*   dxa_ws = (int*)(wsb + WS_DXA);

  snn_pre<<<NBAT, 256, 0, stream>>>(mask, t_ptr, pid, t_last, dtf_ws, dxa_ws, maskws, out);
  snn_gemm<<<dim3(NBAT / BM, N_OUT / BN, SPLITK), 256, 0, stream>>>(
      (const char*)maskws, synw, part);
  snn_reduce<<<(NBAT * N_OUT) / 1024, 256, 0, stream>>>(
      part, memf, memp, tau, vth, mem_map, dtf_ws, dxa_ws, out);
  snn_lut<<<NBAT, 256, 0, stream>>>(memp, dxa_ws, mem_map, lut_in, out);
}

// Round 4
// 48.199 us; speedup vs baseline: 1.6569x; 1.0549x over previous
//
#include <hip/hip_runtime.h>

typedef __attribute__((ext_vector_type(8))) short short8;
typedef __attribute__((ext_vector_type(4))) float f32x4;
typedef unsigned int u32;

#define N_IN  4096
#define N_OUT 4096
#define NBAT  256

#define OUT_ACT   0
#define OUT_FICT  1048576
#define OUT_PHYS  2097152
#define OUT_LUT   3145728
#define OUT_TLAST 3211264

// ws layout (<= 18.9 MB, known-safe)
#define WS_MASK   0                       // 2 MB bf16 mask, pre-swizzled
#define WS_PART   2097152                 // 16 MB fp32 partials [4][256][4096]
#define WS_DTF    (WS_PART + 16777216)
#define WS_DXA    (WS_DTF + 1024)

#define BM 128
#define BN 32
#define BK 64
#define SPLITK 4
#define KCHUNK (N_IN / SPLITK)            // 1024
#define NTK (KCHUNK / BK)                 // 16 K-tiles per block

__device__ __forceinline__ unsigned f2bf(float f) {
  unsigned u = __float_as_uint(f);
  return (u + 0x7FFFu + ((u >> 16) & 1u)) >> 16;   // RNE to bf16
}

__device__ __forceinline__ void gload16(const void* g, void* l) {
  __builtin_amdgcn_global_load_lds(
      (const __attribute__((address_space(1))) u32*)g,
      (__attribute__((address_space(3))) u32*)l, 16, 0, 0);
}

// ---------------------------------------------------------------------------
// Kernel A: prepass. XOR-parity + delta_t + t_last, AND converts mask to a
// pre-swizzled bf16 image (16B unit g' = g ^ (row&7) within each 64-k tile)
// so the GEMM can global_load_lds it linearly and read swizzled.
// ---------------------------------------------------------------------------
__global__ __launch_bounds__(256) void snn_pre(
    const int* __restrict__ mask, const int* __restrict__ t_ptr,
    const int* __restrict__ pid, const int* __restrict__ t_last,
    float* __restrict__ dtf_ws, int* __restrict__ dxa_ws,
    u32* __restrict__ maskws, float* __restrict__ out)
{
  const int b = blockIdx.x, tid = threadIdx.x;
  const int k0 = tid * 16;
  const int4* mp = (const int4*)(mask + (size_t)b * N_IN + k0);
  const int4* pp = (const int4*)(pid + k0);
  int x = 0;
  u32 wv[8];
#pragma unroll
  for (int q = 0; q < 4; ++q) {
    int4 m = mp[q];
    int4 id = pp[q];
    x ^= (m.x ? id.x : 0) ^ (m.y ? id.y : 0) ^ (m.z ? id.z : 0) ^ (m.w ? id.w : 0);
    wv[q * 2]     = (m.x ? 0x3F80u : 0u) | ((m.y ? 0x3F80u : 0u) << 16);
    wv[q * 2 + 1] = (m.z ? 0x3F80u : 0u) | ((m.w ? 0x3F80u : 0u) << 16);
  }
  {
    const int kt = tid >> 2;            // 64-k tile index
    const int gg = (tid & 3) * 2;       // 16B unit within tile
    u32* base = maskws + (size_t)b * 2048 + kt * 32;   // row stride 8192B
    int g0 = gg ^ (b & 7), g1 = (gg + 1) ^ (b & 7);
    uint4 v0; v0.x = wv[0]; v0.y = wv[1]; v0.z = wv[2]; v0.w = wv[3];
    uint4 v1; v1.x = wv[4]; v1.y = wv[5]; v1.z = wv[6]; v1.w = wv[7];
    *(uint4*)(base + g0 * 4) = v0;
    *(uint4*)(base + g1 * 4) = v1;
  }
  x ^= __shfl_xor(x, 32); x ^= __shfl_xor(x, 16); x ^= __shfl_xor(x, 8);
  x ^= __shfl_xor(x, 4);  x ^= __shfl_xor(x, 2);  x ^= __shfl_xor(x, 1);
  __shared__ int wx[4];
  if ((tid & 63) == 0) wx[tid >> 6] = x;
  __syncthreads();
  if (tid == 0) {
    int acc = wx[0] ^ wx[1] ^ wx[2] ^ wx[3];
    int tt = t_ptr[0];
    int dt = (tt - t_last[b]) & 15;
    dtf_ws[b] = (float)dt;
    dxa_ws[b] = dt ^ (acc & 15);
    out[OUT_TLAST + b] = (float)tt;
  }
}

// ---------------------------------------------------------------------------
// Kernel B: bf16 MFMA GEMM, split-K=4. Occupancy-first design:
//   LDS = 40 KB/block -> 4 blocks/CU, grid 1024 -> 16 waves/CU (4/SIMD).
//   A: global_load_lds ring-2, issued 1-ahead post-barrier (pre-swizzled image)
//   B: reg-staged fp32->bf16, depth-2 (modular uniform issue at tail)
//   Explicit counted vmcnt(8)/tile: drains A(t)+B(t+1), leaves B(t+2) in flight.
//   XCD-aware block swizzle: 8 consecutive sids share one B column panel.
// ---------------------------------------------------------------------------
__global__ __launch_bounds__(256) void snn_gemm(
    const char* __restrict__ maskws, const float* __restrict__ synw,
    float* __restrict__ part)
{
  __shared__ __align__(16) char ldsA[2][BM * BK * 2];   // 2 x 16 KB
  __shared__ __align__(16) char ldsB[2][BN * BK * 2];   // 2 x  4 KB

  const int tid = threadIdx.x;
  const int lane = tid & 63, wid = tid >> 6;
  const int l15 = lane & 15, l4 = lane >> 4;

  // bijective XCD swizzle (1024 blocks, 8 XCDs): XCD x gets sids x*128..+127
  const int bid = blockIdx.x;
  const int sid = (bid & 7) * 128 + (bid >> 3);
  const int nb = sid >> 3;          // 0..127  (slow: B panel shared within XCD chunk)
  const int mb = (sid >> 2) & 1;    // 0..1    (mb-pair co-scheduled -> B L2 reuse)
  const int kc = sid & 3;           // 0..3
  const int bmb = mb * BM, bnb = nb * BN, kcb = kc * KCHUNK;

  const char* a_gbase = maskws + (size_t)bmb * 8192 + (size_t)kcb * 2;
  const int b_n = tid & 31;         // column within panel
  const int b_ko = tid >> 5;        // k-octet 0..7
  const float* b_gbase = synw + (size_t)(kcb + b_ko * 8) * N_OUT + bnb + b_n;

  auto issueA = [&](int kt) {       // kt already modular
    char* dbase = &ldsA[kt & 1][wid * 1024];
    const char* g0 = a_gbase + (size_t)(tid >> 3) * 8192 + kt * 128 + (tid & 7) * 16;
#pragma unroll
    for (int i = 0; i < 4; ++i)
      gload16(g0 + (size_t)i * (32 * 8192), dbase + i * 4096);
  };
  auto loadB = [&](int kt, float* bv) {
    const float* g = b_gbase + (size_t)kt * BK * N_OUT;
#pragma unroll
    for (int j = 0; j < 8; ++j) bv[j] = g[(size_t)j * N_OUT];
  };
  auto writeB = [&](const float* bv, int buf) {
    u32 w[4];
#pragma unroll
    for (int p = 0; p < 4; ++p) w[p] = f2bf(bv[2 * p]) | (f2bf(bv[2 * p + 1]) << 16);
    uint4 v; v.x = w[0]; v.y = w[1]; v.z = w[2]; v.w = w[3];
    *(uint4*)(&ldsB[buf][b_n * 128 + ((b_ko ^ (b_n & 7)) * 16)]) = v;
  };

  f32x4 acc[2][2] = {};

  auto compute = [&](int buf) {
#pragma unroll
    for (int kk = 0; kk < 2; ++kk) {
      const int g0 = kk * 4 + l4;
      short8 a[2], b[2];
#pragma unroll
      for (int mi = 0; mi < 2; ++mi) {
        int row = wid * 32 + mi * 16 + l15;
        a[mi] = *(const short8*)(&ldsA[buf][row * 128 + ((g0 ^ (row & 7)) * 16)]);
      }
#pragma unroll
      for (int nj = 0; nj < 2; ++nj) {
        int col = nj * 16 + l15;
        b[nj] = *(const short8*)(&ldsB[buf][col * 128 + ((g0 ^ (col & 7)) * 16)]);
      }
#pragma unroll
      for (int mi = 0; mi < 2; ++mi)
#pragma unroll
        for (int nj = 0; nj < 2; ++nj)
          acc[mi][nj] = __builtin_amdgcn_mfma_f32_16x16x32_bf16(a[mi], b[nj], acc[mi][nj], 0, 0, 0);
    }
  };

  float bvA[8], bvB[8];

  // prologue: A(0)[4], B(0)[8], B(1)[8] in flight
  issueA(0);
  loadB(0, bvA);
  loadB(1, bvB);

  // Per iter t: writeB(t) [B(t) drained by prev vmcnt(8)]; reload same set with
  // B(t+2); vmcnt(8) leaves exactly B(t+2)'s 8 loads, drains A(t)+B(t+1);
  // barrier; issueA(t+1) post-barrier (ring-2 safe: buf (t+1)&1 last read at
  // compute(t-1), finished by all waves pre-barrier); compute(t).
#define BODY(KT, CURBV)                                            \
  {                                                                \
    writeB(CURBV, (KT) & 1);                                       \
    loadB(((KT) + 2) & 15, CURBV);                                 \
    __builtin_amdgcn_sched_barrier(0);                             \
    asm volatile("s_waitcnt vmcnt(8) lgkmcnt(0)" ::: "memory");    \
    __builtin_amdgcn_s_barrier();                                  \
    __builtin_amdgcn_sched_barrier(0);                             \
    issueA(((KT) + 1) & 15);                                       \
    compute((KT) & 1);                                             \
  }

  for (int kt = 0; kt < NTK; kt += 2) {
    BODY(kt, bvA);
    BODY(kt + 1, bvB);
  }
#undef BODY

  float* pb = part + (size_t)kc * (NBAT * N_OUT);
#pragma unroll
  for (int mi = 0; mi < 2; ++mi)
#pragma unroll
    for (int nj = 0; nj < 2; ++nj) {
      const int o = bnb + nj * 16 + l15;
#pragma unroll
      for (int r = 0; r < 4; ++r) {
        const int b = bmb + wid * 32 + mi * 16 + l4 * 4 + r;
        pb[(size_t)b * N_OUT + o] = acc[mi][nj][r];
      }
    }
}

// ---------------------------------------------------------------------------
// Kernel C: split-K reduce + fused epilogue (decay, phys, act).
// ---------------------------------------------------------------------------
__global__ __launch_bounds__(256) void snn_reduce(
    const float* __restrict__ part, const float* __restrict__ memf,
    const int* __restrict__ memp, const float* __restrict__ tau,
    const float* __restrict__ vth, const float* __restrict__ mem_map,
    const float* __restrict__ dtf_ws, const int* __restrict__ dxa_ws,
    float* __restrict__ out)
{
  const int flat = (blockIdx.x * 256 + threadIdx.x) * 4;
  const int b = flat >> 12, o = flat & 4095;
  const float4 p0 = *(const float4*)(part + flat);
  const float4 p1 = *(const float4*)(part + 1048576 + flat);
  const float4 p2 = *(const float4*)(part + 2097152 + flat);
  const float4 p3 = *(const float4*)(part + 3145728 + flat);
  float4 ws;
  ws.x = (p0.x + p1.x) + (p2.x + p3.x);
  ws.y = (p0.y + p1.y) + (p2.y + p3.y);
  ws.z = (p0.z + p1.z) + (p2.z + p3.z);
  ws.w = (p0.w + p1.w) + (p2.w + p3.w);
  const float dtf = dtf_ws[b];
  const int dxa = dxa_ws[b];
  const float4 mf = *(const float4*)(memf + flat);
  const int4  mp = *(const int4*)(memp + flat);
  const float4 tv = *(const float4*)(tau + o);
  const float4 vv = *(const float4*)(vth + o);
  float4 act, fict, phys;
#define DO(c, oi) { float d = __expf(-tv.c * dtf); fict.c = mf.c * d + ws.c; \
                    int mpn = (mp.c ^ dxa) & 15; phys.c = (float)mpn; \
                    act.c = (mem_map[(o + oi) * 16 + mpn] >= vv.c) ? 1.f : 0.f; }
  DO(x, 0) DO(y, 1) DO(z, 2) DO(w, 3)
#undef DO
  *(float4*)(out + OUT_ACT  + flat) = act;
  *(float4*)(out + OUT_FICT + flat) = fict;
  *(float4*)(out + OUT_PHYS + flat) = phys;
}

// ---------------------------------------------------------------------------
// Kernel D: LUT scatter-add collapsed to per-(o,m) histogram.
// ---------------------------------------------------------------------------
__global__ __launch_bounds__(256) void snn_lut(
    const int* __restrict__ memp, const int* __restrict__ dxa_ws,
    const float* __restrict__ mem_map, const float* __restrict__ lut_in,
    float* __restrict__ out)
{
  __shared__ int mp[NBAT * 16];
  __shared__ int dxs[NBAT];
  const int tid = threadIdx.x;
  const int o0 = blockIdx.x * 16;
#pragma unroll
  for (int i = 0; i < 16; ++i) {
    int b = i * 16 + (tid >> 4);
    int oj = tid & 15;
    mp[b * 16 + oj] = memp[(size_t)b * N_OUT + o0 + oj];
  }
  dxs[tid] = dxa_ws[tid];
  __syncthreads();
  const int o_l = tid >> 4, m = tid & 15;
  int cnt = 0;
#pragma unroll 8
  for (int b = 0; b < NBAT; ++b) {
    int v = (mp[b * 16 + o_l] ^ dxs[b]) & 15;
    cnt += (v == m);
  }
  const int o = o0 + o_l;
  const float vmap = mem_map[o * 16 + m];
  out[OUT_LUT + o * 16 + m] = lut_in[o * 16 + m] + 0.5f * ((float)m - vmap) * (float)cnt;
}

// ---------------------------------------------------------------------------
extern "C" void kernel_launch(void* const* d_in, const int* in_sizes, int n_in,
                              void* d_out, int out_size, void* d_ws, size_t ws_size,
                              hipStream_t stream)
{
  const int*   mask    = (const int*)d_in[0];
  const int*   t_ptr   = (const int*)d_in[1];
  const int*   pid     = (const int*)d_in[2];
  const int*   t_last  = (const int*)d_in[3];
  const float* memf    = (const float*)d_in[4];
  const int*   memp    = (const int*)d_in[5];
  const float* lut_in  = (const float*)d_in[6];
  const float* tau     = (const float*)d_in[7];
  const float* vth     = (const float*)d_in[8];
  const float* synw    = (const float*)d_in[9];
  const float* mem_map = (const float*)d_in[10];
  float* out = (float*)d_out;

  char* wsb = (char*)d_ws;
  u32*   maskws = (u32*)(wsb + WS_MASK);
  float* part   = (float*)(wsb + WS_PART);
  float* dtf_ws = (float*)(wsb + WS_DTF);
  int*   dxa_ws = (int*)(wsb + WS_DXA);

  snn_pre<<<NBAT, 256, 0, stream>>>(mask, t_ptr, pid, t_last, dtf_ws, dxa_ws, maskws, out);
  snn_gemm<<<(NBAT / BM) * (N_OUT / BN) * SPLITK, 256, 0, stream>>>(
      (const char*)maskws, synw, part);
  snn_reduce<<<(NBAT * N_OUT) / 1024, 256, 0, stream>>>(
      part, memf, memp, tau, vth, mem_map, dtf_ws, dxa_ws, out);
  snn_lut<<<NBAT, 256, 0, stream>>>(memp, dxa_ws, mem_map, lut_in, out);
}